// Round 1
// baseline (630.154 us; speedup 1.0000x reference)
//
#include <hip/hip_runtime.h>
#include <hip/hip_bf16.h>

// QuantLinear: out[m][n] = (sum_k in[m][k] * (q[n][k]-128)) * scale[n] + bias[n]
// M=512 (B*S), K=4096 (IN), N=11008 (OUT). A fp32, Q int32 (0..255), out fp32.
// Strategy: bf16 MFMA GEMM, dequant folded into epilogue; (q-128) exact in bf16.

#define BM 128
#define BN 128
#define BK 64

typedef __attribute__((ext_vector_type(8))) short bf16x8;
typedef __attribute__((ext_vector_type(4))) float f32x4;

__device__ __forceinline__ unsigned short f2bf(float x) {
  union { float f; unsigned u; } c; c.f = x;
  unsigned r = (c.u + 0x7FFFu + ((c.u >> 16) & 1u)) >> 16;
  return (unsigned short)r;
}

__global__ __launch_bounds__(256, 2)
void qlinear_kernel(const float* __restrict__ A,     // [M][K]
                    const int*   __restrict__ Q,     // [N][K]
                    const float* __restrict__ scale, // [N]
                    const float* __restrict__ bias,  // [N]
                    float* __restrict__ C,           // [M][N]
                    int M, int N, int K)
{
  __shared__ unsigned short sA[BM][BK];
  __shared__ unsigned short sB[BN][BK];

  const int tid  = threadIdx.x;
  const int lane = tid & 63;
  const int wave = tid >> 6;
  const int wr   = wave >> 1;   // 0..1 : wave row in 2x2 wave grid
  const int wc   = wave & 1;    // 0..1 : wave col

  const int nbm  = M / BM;                  // 4
  const int bm   = blockIdx.x % nbm;        // M fastest: B-panel reuse across
  const int bn   = blockIdx.x / nbm;        // concurrently-resident blocks
  const int row0 = bm * BM;
  const int col0 = bn * BN;

  f32x4 acc[4][4];
#pragma unroll
  for (int i = 0; i < 4; ++i)
#pragma unroll
    for (int j = 0; j < 4; ++j)
      acc[i][j] = (f32x4)0.0f;

  // staging decomposition: 16 threads per row (16B each), 16 rows per iter
  const int sr = tid >> 4;          // 0..15
  const int sc = (tid & 15) << 2;   // element col, 0..60 step 4

  for (int kt = 0; kt < K; kt += BK) {
#pragma unroll
    for (int it = 0; it < 8; ++it) {
      const int r = it * 16 + sr;
      const float4 va = *reinterpret_cast<const float4*>(A + (size_t)(row0 + r) * K + kt + sc);
      const int4   vb = *reinterpret_cast<const int4*>(Q + (size_t)(col0 + r) * K + kt + sc);
      ushort4 ha, hb;
      ha.x = f2bf(va.x); ha.y = f2bf(va.y); ha.z = f2bf(va.z); ha.w = f2bf(va.w);
      hb.x = f2bf((float)(vb.x - 128));
      hb.y = f2bf((float)(vb.y - 128));
      hb.z = f2bf((float)(vb.z - 128));
      hb.w = f2bf((float)(vb.w - 128));
      *reinterpret_cast<ushort4*>(&sA[r][sc]) = ha;
      *reinterpret_cast<ushort4*>(&sB[r][sc]) = hb;
    }
    __syncthreads();

#pragma unroll
    for (int kk = 0; kk < BK; kk += 32) {
      const int kb = kk + ((lane >> 4) << 3);
      bf16x8 af[4], bfr[4];
#pragma unroll
      for (int mi = 0; mi < 4; ++mi)
        af[mi] = *reinterpret_cast<const bf16x8*>(&sA[wr * 64 + mi * 16 + (lane & 15)][kb]);
#pragma unroll
      for (int ni = 0; ni < 4; ++ni)
        bfr[ni] = *reinterpret_cast<const bf16x8*>(&sB[wc * 64 + ni * 16 + (lane & 15)][kb]);
#pragma unroll
      for (int mi = 0; mi < 4; ++mi)
#pragma unroll
        for (int ni = 0; ni < 4; ++ni)
          acc[mi][ni] = __builtin_amdgcn_mfma_f32_16x16x32_bf16(af[mi], bfr[ni], acc[mi][ni], 0, 0, 0);
    }
    __syncthreads();
  }

  // epilogue: D col = lane&15 (n), row = (lane>>4)*4 + reg (m)  [m89/m91 layout]
  const int cl = lane & 15;
  const int rb = row0 + wr * 64 + ((lane >> 4) << 2);
#pragma unroll
  for (int ni = 0; ni < 4; ++ni) {
    const int n = col0 + wc * 64 + ni * 16 + cl;
    const float s = scale[n];
    const float b = bias[n];
#pragma unroll
    for (int mi = 0; mi < 4; ++mi) {
#pragma unroll
      for (int r = 0; r < 4; ++r) {
        C[(size_t)(rb + mi * 16 + r) * N + n] = acc[mi][ni][r] * s + b;
      }
    }
  }
}

extern "C" void kernel_launch(void* const* d_in, const int* in_sizes, int n_in,
                              void* d_out, int out_size, void* d_ws, size_t ws_size,
                              hipStream_t stream) {
  const float* inp   = (const float*)d_in[0];
  const int*   qw    = (const int*)d_in[1];
  const float* scale = (const float*)d_in[2];
  const float* bias  = (const float*)d_in[3];
  float*       out   = (float*)d_out;

  const int OUT = in_sizes[3];            // 11008
  const int IN  = in_sizes[1] / OUT;      // 4096
  const int M   = in_sizes[0] / IN;       // 512

  const int grid = (M / BM) * (OUT / BN); // 4 * 86 = 344
  qlinear_kernel<<<grid, 256, 0, stream>>>(inp, qw, scale, bias, out, M, OUT, IN);
}

// Round 2
// 396.476 us; speedup vs baseline: 1.5894x; 1.5894x over previous
//
#include <hip/hip_runtime.h>
#include <hip/hip_bf16.h>

// QuantLinear: out[m][n] = (sum_k in[m][k] * (q[n][k]-128)) * scale[n] + bias[n]
// M=512, K=4096, N=11008. A fp32, Q int32 (0..255), out fp32.
// bf16 MFMA GEMM; dequant scale folded into epilogue; (q-128) exact in bf16.
// R2: BM=64 (688 blocks, ~90% balance), double-buffered LDS + register
// prefetch (T14: issue loads before MFMA, convert+write after), XOR-swizzled
// LDS (T2) to kill the 16-way ds_read_b128 conflict.

#define BM 64
#define BN 128
#define BK 64

typedef __attribute__((ext_vector_type(8))) short bf16x8;
typedef __attribute__((ext_vector_type(4))) float f32x4;

__device__ __forceinline__ unsigned short f2bf(float x) {
  __hip_bfloat16 h = __float2bfloat16(x);
  return *reinterpret_cast<unsigned short*>(&h);
}

__global__ __launch_bounds__(256, 3)
void qlinear_kernel(const float* __restrict__ A,     // [M][K]
                    const int*   __restrict__ Q,     // [N][K]
                    const float* __restrict__ scale, // [N]
                    const float* __restrict__ bias,  // [N]
                    float* __restrict__ C,           // [M][N]
                    int M, int N, int K)
{
  __shared__ unsigned short sA[2][BM][BK];  // 2 x 8 KB
  __shared__ unsigned short sB[2][BN][BK];  // 2 x 16 KB  (48 KB total -> 3 blk/CU)

  const int tid  = threadIdx.x;
  const int lane = tid & 63;
  const int wave = tid >> 6;
  const int wr   = wave >> 1;   // 0..1, 32-row strip
  const int wc   = wave & 1;    // 0..1, 64-col strip

  const int nbm  = M / BM;                  // 8
  const int bm   = blockIdx.x % nbm;        // M fastest: Q-panel shared by
  const int bn   = blockIdx.x / nbm;        // concurrently-resident M-blocks
  const int row0 = bm * BM;
  const int col0 = bn * BN;

  // staging: 16 threads per row (16B each), 16 rows per iter
  const int sr   = tid >> 4;                // 0..15
  const int scol = (tid & 15) << 2;         // 0,4,...,60

  const float* Abase = A + (size_t)(row0 + sr) * K + scol;
  const int*   Qbase = Q + (size_t)(col0 + sr) * K + scol;

  f32x4 acc[2][4];
#pragma unroll
  for (int i = 0; i < 2; ++i)
#pragma unroll
    for (int j = 0; j < 4; ++j)
      acc[i][j] = (f32x4)0.0f;

  float4 pa[4];   // A prefetch: 4 iters x 16 rows
  int4   pq[8];   // Q prefetch: 8 iters x 16 rows

  auto LOADS = [&](int ke) {  // ke = element offset along K
#pragma unroll
    for (int it = 0; it < 4; ++it)
      pa[it] = *reinterpret_cast<const float4*>(Abase + (size_t)(it * 16) * K + ke);
#pragma unroll
    for (int it = 0; it < 8; ++it)
      pq[it] = *reinterpret_cast<const int4*>(Qbase + (size_t)(it * 16) * K + ke);
  };

  auto STORES = [&](int b) {  // convert + swizzled LDS write
#pragma unroll
    for (int it = 0; it < 4; ++it) {
      const int r = it * 16 + sr;
      const int c = scol ^ ((r & 7) << 3);
      ushort4 h;
      h.x = f2bf(pa[it].x); h.y = f2bf(pa[it].y);
      h.z = f2bf(pa[it].z); h.w = f2bf(pa[it].w);
      *reinterpret_cast<ushort4*>(&sA[b][r][c]) = h;
    }
#pragma unroll
    for (int it = 0; it < 8; ++it) {
      const int r = it * 16 + sr;
      const int c = scol ^ ((r & 7) << 3);
      const int4 v = pq[it];
      ushort4 h;
      h.x = f2bf((float)(v.x - 128));
      h.y = f2bf((float)(v.y - 128));
      h.z = f2bf((float)(v.z - 128));
      h.w = f2bf((float)(v.w - 128));
      *reinterpret_cast<ushort4*>(&sB[b][r][c]) = h;
    }
  };

  const int NT = K / BK;  // 64
  LOADS(0);
  STORES(0);
  __syncthreads();

  for (int kt = 0; kt < NT; ++kt) {
    const int cur = kt & 1;
    if (kt + 1 < NT) LOADS((kt + 1) * BK);   // issue early — hides under MFMA

#pragma unroll
    for (int kk = 0; kk < BK; kk += 32) {
      const int kb = kk + ((lane >> 4) << 3);
      bf16x8 af[2], bv[4];
#pragma unroll
      for (int mi = 0; mi < 2; ++mi) {
        const int r = wr * 32 + mi * 16 + (lane & 15);
        af[mi] = *reinterpret_cast<const bf16x8*>(&sA[cur][r][kb ^ ((r & 7) << 3)]);
      }
#pragma unroll
      for (int ni = 0; ni < 4; ++ni) {
        const int r = wc * 64 + ni * 16 + (lane & 15);
        bv[ni] = *reinterpret_cast<const bf16x8*>(&sB[cur][r][kb ^ ((r & 7) << 3)]);
      }
#pragma unroll
      for (int mi = 0; mi < 2; ++mi)
#pragma unroll
        for (int ni = 0; ni < 4; ++ni)
          acc[mi][ni] = __builtin_amdgcn_mfma_f32_16x16x32_bf16(af[mi], bv[ni], acc[mi][ni], 0, 0, 0);
    }

    if (kt + 1 < NT) STORES(cur ^ 1);        // vmcnt wait lands here, after MFMA
    __syncthreads();
  }

  // epilogue: D col = lane&15 (n), row = (lane>>4)*4 + reg (m)  [m89/m91]
  const int cl = lane & 15;
  const int rb = row0 + wr * 32 + ((lane >> 4) << 2);
#pragma unroll
  for (int ni = 0; ni < 4; ++ni) {
    const int n = col0 + wc * 64 + ni * 16 + cl;
    const float s = scale[n];
    const float b = bias[n];
#pragma unroll
    for (int mi = 0; mi < 2; ++mi) {
#pragma unroll
      for (int r = 0; r < 4; ++r) {
        C[(size_t)(rb + mi * 16 + r) * N + n] = acc[mi][ni][r] * s + b;
      }
    }
  }
}

extern "C" void kernel_launch(void* const* d_in, const int* in_sizes, int n_in,
                              void* d_out, int out_size, void* d_ws, size_t ws_size,
                              hipStream_t stream) {
  const float* inp   = (const float*)d_in[0];
  const int*   qw    = (const int*)d_in[1];
  const float* scale = (const float*)d_in[2];
  const float* bias  = (const float*)d_in[3];
  float*       out   = (float*)d_out;

  const int OUT = in_sizes[3];            // 11008
  const int IN  = in_sizes[1] / OUT;      // 4096
  const int M   = in_sizes[0] / IN;       // 512

  const int grid = (M / BM) * (OUT / BN); // 8 * 86 = 688
  qlinear_kernel<<<grid, 256, 0, stream>>>(inp, qw, scale, bias, out, M, OUT, IN);
}

// Round 3
// 360.564 us; speedup vs baseline: 1.7477x; 1.0996x over previous
//
#include <hip/hip_runtime.h>
#include <hip/hip_bf16.h>

// QuantLinear: out[m][n] = (sum_k in[m][k] * (q[n][k]-128)) * scale[n] + bias[n]
// M=512, K=4096, N=11008. A fp32, Q int32 (0..255), out fp32.
// bf16 MFMA GEMM; dequant folded into epilogue; (q-128) exact in bf16.
// R3: 2-deep named-register pipeline + sched_barrier issue pins + raw
// s_barrier (no vmcnt drain -> counted waits, T4) + bijective XCD swizzle (T1).

#define BM 64
#define BN 128
#define BK 64

typedef __attribute__((ext_vector_type(8))) short bf16x8;
typedef __attribute__((ext_vector_type(4))) float f32x4;

__device__ __forceinline__ unsigned short f2bf(float x) {
  __hip_bfloat16 h = __float2bfloat16(x);
  return *reinterpret_cast<unsigned short*>(&h);
}

__global__ __launch_bounds__(256, 2)
void qlinear_kernel(const float* __restrict__ A,     // [M][K]
                    const int*   __restrict__ Q,     // [N][K]
                    const float* __restrict__ scale, // [N]
                    const float* __restrict__ bias,  // [N]
                    float* __restrict__ C,           // [M][N]
                    int M, int N, int K)
{
  __shared__ unsigned short sA[2][BM][BK];  // 2 x 8 KB
  __shared__ unsigned short sB[2][BN][BK];  // 2 x 16 KB

  const int tid  = threadIdx.x;
  const int lane = tid & 63;
  const int wave = tid >> 6;
  const int wr   = wave >> 1;   // 0..1, 32-row strip
  const int wc   = wave & 1;    // 0..1, 64-col strip

  // --- bijective XCD-chunked swizzle: each XCD gets a contiguous wgid range
  // (panel-sharing M-blocks colocate on one XCD's L2).
  const int nbm = M / BM;                   // 8
  const int nwg = gridDim.x;                // 688
  int wgid = blockIdx.x;
  if ((nwg & 7) == 0) {
    wgid = (wgid & 7) * (nwg >> 3) + (wgid >> 3);
  }
  const int bm   = wgid % nbm;              // M fastest within XCD chunk
  const int bn   = wgid / nbm;
  const int row0 = bm * BM;
  const int col0 = bn * BN;

  // staging: 16 threads per row (16B each), 16 rows per pass
  const int sr   = tid >> 4;                // 0..15
  const int scol = (tid & 15) << 2;         // 0,4,...,60

  const float* Abase = A + (size_t)(row0 + sr) * K + scol;
  const int*   Qbase = Q + (size_t)(col0 + sr) * K + scol;

  f32x4 acc[2][4];
#pragma unroll
  for (int i = 0; i < 2; ++i)
#pragma unroll
    for (int j = 0; j < 4; ++j)
      acc[i][j] = (f32x4)0.0f;

  // two NAMED prefetch register sets (rule #20: static indexing only)
  float4 pa0[4], pa1[4];
  int4   pq0[8], pq1[8];

  auto LOADS = [&](float4* pa, int4* pq, int ke) {
#pragma unroll
    for (int it = 0; it < 4; ++it)
      pa[it] = *reinterpret_cast<const float4*>(Abase + (size_t)(it * 16) * K + ke);
#pragma unroll
    for (int it = 0; it < 8; ++it)
      pq[it] = *reinterpret_cast<const int4*>(Qbase + (size_t)(it * 16) * K + ke);
  };

  auto STORES = [&](const float4* pa, const int4* pq, int b) {
#pragma unroll
    for (int it = 0; it < 4; ++it) {
      const int r = it * 16 + sr;
      const int c = scol ^ ((r & 7) << 3);
      ushort4 h;
      h.x = f2bf(pa[it].x); h.y = f2bf(pa[it].y);
      h.z = f2bf(pa[it].z); h.w = f2bf(pa[it].w);
      *reinterpret_cast<ushort4*>(&sA[b][r][c]) = h;
    }
#pragma unroll
    for (int it = 0; it < 8; ++it) {
      const int r = it * 16 + sr;
      const int c = scol ^ ((r & 7) << 3);
      const int4 v = pq[it];
      ushort4 h;
      h.x = f2bf((float)(v.x - 128));
      h.y = f2bf((float)(v.y - 128));
      h.z = f2bf((float)(v.z - 128));
      h.w = f2bf((float)(v.w - 128));
      *reinterpret_cast<ushort4*>(&sB[b][r][c]) = h;
    }
  };

  auto COMPUTE = [&](int b) {
#pragma unroll
    for (int kk = 0; kk < BK; kk += 32) {
      const int kb = kk + ((lane >> 4) << 3);
      bf16x8 af[2], bv[4];
#pragma unroll
      for (int mi = 0; mi < 2; ++mi) {
        const int r = wr * 32 + mi * 16 + (lane & 15);
        af[mi] = *reinterpret_cast<const bf16x8*>(&sA[b][r][kb ^ ((r & 7) << 3)]);
      }
#pragma unroll
      for (int ni = 0; ni < 4; ++ni) {
        const int r = wc * 64 + ni * 16 + (lane & 15);
        bv[ni] = *reinterpret_cast<const bf16x8*>(&sB[b][r][kb ^ ((r & 7) << 3)]);
      }
#pragma unroll
      for (int mi = 0; mi < 2; ++mi)
#pragma unroll
        for (int ni = 0; ni < 4; ++ni)
          acc[mi][ni] = __builtin_amdgcn_mfma_f32_16x16x32_bf16(af[mi], bv[ni], acc[mi][ni], 0, 0, 0);
    }
  };

  auto BAR = [&]() {
    // drain LDS ops (ds_writes visible; ds_reads landed) but NOT vmcnt:
    // prefetched global loads stay in flight across the barrier (T4).
    asm volatile("s_waitcnt lgkmcnt(0)" ::: "memory");
    __builtin_amdgcn_s_barrier();
  };

  const int NT = K / BK;  // 64 (even)

  LOADS(pa0, pq0, 0);
  LOADS(pa1, pq1, BK);
  __builtin_amdgcn_sched_barrier(0);
  STORES(pa0, pq0, 0);    // waits only set0 (counted vmcnt; set1 in flight)
  BAR();

  for (int t = 0; t < NT; t += 2) {
    // ---- tile t from buf0 ----
    if (t + 2 < NT) LOADS(pa0, pq0, (t + 2) * BK);
    __builtin_amdgcn_sched_barrier(0);   // pin: loads may not sink below
    COMPUTE(0);
    STORES(pa1, pq1, 1);                 // tile t+1 -> buf1 (t+1 < NT always)
    BAR();

    // ---- tile t+1 from buf1 ----
    if (t + 3 < NT) LOADS(pa1, pq1, (t + 3) * BK);
    __builtin_amdgcn_sched_barrier(0);
    COMPUTE(1);
    if (t + 2 < NT) STORES(pa0, pq0, 0); // tile t+2 -> buf0
    BAR();
  }

  // epilogue: D col = lane&15 (n), row = (lane>>4)*4 + reg (m)  [m89/m91]
  const int cl = lane & 15;
  const int rb = row0 + wr * 32 + ((lane >> 4) << 2);
#pragma unroll
  for (int ni = 0; ni < 4; ++ni) {
    const int n = col0 + wc * 64 + ni * 16 + cl;
    const float s = scale[n];
    const float b = bias[n];
#pragma unroll
    for (int mi = 0; mi < 2; ++mi) {
#pragma unroll
      for (int r = 0; r < 4; ++r) {
        C[(size_t)(rb + mi * 16 + r) * N + n] = acc[mi][ni][r] * s + b;
      }
    }
  }
}

extern "C" void kernel_launch(void* const* d_in, const int* in_sizes, int n_in,
                              void* d_out, int out_size, void* d_ws, size_t ws_size,
                              hipStream_t stream) {
  const float* inp   = (const float*)d_in[0];
  const int*   qw    = (const int*)d_in[1];
  const float* scale = (const float*)d_in[2];
  const float* bias  = (const float*)d_in[3];
  float*       out   = (float*)d_out;

  const int OUT = in_sizes[3];            // 11008
  const int IN  = in_sizes[1] / OUT;      // 4096
  const int M   = in_sizes[0] / IN;       // 512

  const int grid = (M / BM) * (OUT / BN); // 8 * 86 = 688
  qlinear_kernel<<<grid, 256, 0, stream>>>(inp, qw, scale, bias, out, M, OUT, IN);
}

// Round 4
// 358.219 us; speedup vs baseline: 1.7591x; 1.0065x over previous
//
#include <hip/hip_runtime.h>
#include <hip/hip_bf16.h>

// QuantLinear: out[m][n] = (sum_k in[m][k]*(q[n][k]-128)) * scale[n] + bias[n]
// M=512, K=4096, N=11008. A fp32, Q int32 (0..255), out fp32.
// R4: named-scalar prefetch registers via macros (rule #20 fix — R3's lambda
// pointer params sent the prefetch sets to scratch, VGPR=120 proved it).
// Rowsum trick: stage bf16(q) exactly (q in [0,255] exact in bf16), subtract
// 128*rowsum(A) in the epilogue. 2-deep pipeline, no vmcnt drain at barriers.

#define BM 64
#define BN 128
#define BK 64

typedef __attribute__((ext_vector_type(8))) short bf16x8;
typedef __attribute__((ext_vector_type(4))) float f32x4;

__device__ __forceinline__ unsigned short f2bf(float x) {
  __hip_bfloat16 h = __float2bfloat16(x);
  return *reinterpret_cast<unsigned short*>(&h);
}

__global__ __launch_bounds__(256)
void rowsum_kernel(const float* __restrict__ A, float* __restrict__ rs, int K) {
  const int row = blockIdx.x;
  const int tid = threadIdx.x;
  const float4* Ar = reinterpret_cast<const float4*>(A + (size_t)row * K);
  const int nv4 = K >> 2;
  float s = 0.f;
  for (int i = tid; i < nv4; i += 256) {
    float4 v = Ar[i];
    s += (v.x + v.y) + (v.z + v.w);
  }
#pragma unroll
  for (int off = 32; off > 0; off >>= 1) s += __shfl_down(s, off, 64);
  __shared__ float ws[4];
  if ((tid & 63) == 0) ws[tid >> 6] = s;
  __syncthreads();
  if (tid == 0) rs[row] = (ws[0] + ws[1]) + (ws[2] + ws[3]);
}

// ---- macros over NAMED registers (no arrays through pointers) ----
#define LOADS(s, ke) do {                                                   \
  a##s##_0 = *(const float4*)(Abase + (size_t)( 0) * K + (ke));             \
  a##s##_1 = *(const float4*)(Abase + (size_t)(16) * K + (ke));             \
  a##s##_2 = *(const float4*)(Abase + (size_t)(32) * K + (ke));             \
  a##s##_3 = *(const float4*)(Abase + (size_t)(48) * K + (ke));             \
  q##s##_0 = *(const int4*)(Qbase + (size_t)(  0) * K + (ke));              \
  q##s##_1 = *(const int4*)(Qbase + (size_t)( 16) * K + (ke));              \
  q##s##_2 = *(const int4*)(Qbase + (size_t)( 32) * K + (ke));              \
  q##s##_3 = *(const int4*)(Qbase + (size_t)( 48) * K + (ke));              \
  q##s##_4 = *(const int4*)(Qbase + (size_t)( 64) * K + (ke));              \
  q##s##_5 = *(const int4*)(Qbase + (size_t)( 80) * K + (ke));              \
  q##s##_6 = *(const int4*)(Qbase + (size_t)( 96) * K + (ke));              \
  q##s##_7 = *(const int4*)(Qbase + (size_t)(112) * K + (ke));              \
} while (0)

#define ST_A(s, b, it, reg) do {                                            \
  ushort4 h;                                                                \
  h.x = f2bf(reg.x); h.y = f2bf(reg.y); h.z = f2bf(reg.z); h.w = f2bf(reg.w); \
  *(ushort4*)&sA[b][(it)*16 + sr][swzc] = h;                                \
} while (0)

#define ST_Q(s, b, it, reg) do {                                            \
  ushort4 h;                                                                \
  h.x = f2bf((float)reg.x); h.y = f2bf((float)reg.y);                       \
  h.z = f2bf((float)reg.z); h.w = f2bf((float)reg.w);                       \
  *(ushort4*)&sB[b][(it)*16 + sr][swzc] = h;                                \
} while (0)

#define STORES(s, b) do {                                                   \
  ST_A(s, b, 0, a##s##_0); ST_A(s, b, 1, a##s##_1);                         \
  ST_A(s, b, 2, a##s##_2); ST_A(s, b, 3, a##s##_3);                         \
  ST_Q(s, b, 0, q##s##_0); ST_Q(s, b, 1, q##s##_1);                         \
  ST_Q(s, b, 2, q##s##_2); ST_Q(s, b, 3, q##s##_3);                         \
  ST_Q(s, b, 4, q##s##_4); ST_Q(s, b, 5, q##s##_5);                         \
  ST_Q(s, b, 6, q##s##_6); ST_Q(s, b, 7, q##s##_7);                         \
} while (0)

#define COMPUTE(b) do {                                                     \
  _Pragma("unroll")                                                         \
  for (int kk = 0; kk < BK; kk += 32) {                                     \
    const int kb  = (kk + ((lane >> 4) << 3)) ^ ((lane & 7) << 3);          \
    bf16x8 af0 = *(const bf16x8*)&sA[b][wr*32 +  0 + (lane & 15)][kb];      \
    bf16x8 af1 = *(const bf16x8*)&sA[b][wr*32 + 16 + (lane & 15)][kb];      \
    bf16x8 bv0 = *(const bf16x8*)&sB[b][wc*64 +  0 + (lane & 15)][kb];      \
    bf16x8 bv1 = *(const bf16x8*)&sB[b][wc*64 + 16 + (lane & 15)][kb];      \
    bf16x8 bv2 = *(const bf16x8*)&sB[b][wc*64 + 32 + (lane & 15)][kb];      \
    bf16x8 bv3 = *(const bf16x8*)&sB[b][wc*64 + 48 + (lane & 15)][kb];      \
    acc[0][0] = __builtin_amdgcn_mfma_f32_16x16x32_bf16(af0, bv0, acc[0][0], 0,0,0); \
    acc[0][1] = __builtin_amdgcn_mfma_f32_16x16x32_bf16(af0, bv1, acc[0][1], 0,0,0); \
    acc[0][2] = __builtin_amdgcn_mfma_f32_16x16x32_bf16(af0, bv2, acc[0][2], 0,0,0); \
    acc[0][3] = __builtin_amdgcn_mfma_f32_16x16x32_bf16(af0, bv3, acc[0][3], 0,0,0); \
    acc[1][0] = __builtin_amdgcn_mfma_f32_16x16x32_bf16(af1, bv0, acc[1][0], 0,0,0); \
    acc[1][1] = __builtin_amdgcn_mfma_f32_16x16x32_bf16(af1, bv1, acc[1][1], 0,0,0); \
    acc[1][2] = __builtin_amdgcn_mfma_f32_16x16x32_bf16(af1, bv2, acc[1][2], 0,0,0); \
    acc[1][3] = __builtin_amdgcn_mfma_f32_16x16x32_bf16(af1, bv3, acc[1][3], 0,0,0); \
  }                                                                         \
} while (0)

#define BAR() do {                                                          \
  asm volatile("s_waitcnt lgkmcnt(0)" ::: "memory");                        \
  __builtin_amdgcn_s_barrier();                                             \
} while (0)

__global__ __launch_bounds__(256, 2)
void qlinear_kernel(const float* __restrict__ A,     // [M][K]
                    const int*   __restrict__ Q,     // [N][K]
                    const float* __restrict__ scale, // [N]
                    const float* __restrict__ bias,  // [N]
                    const float* __restrict__ rowsum,// [M]
                    float* __restrict__ C,           // [M][N]
                    int M, int N, int K)
{
  __shared__ unsigned short sA[2][BM][BK];
  __shared__ unsigned short sB[2][BN][BK];

  const int tid  = threadIdx.x;
  const int lane = tid & 63;
  const int wave = tid >> 6;
  const int wr   = wave >> 1;
  const int wc   = wave & 1;

  const int nbm = M / BM;                 // 8
  const int nwg = gridDim.x;              // 688
  int wgid = blockIdx.x;
  if ((nwg & 7) == 0) wgid = (wgid & 7) * (nwg >> 3) + (wgid >> 3);
  const int bm   = wgid % nbm;
  const int bn   = wgid / nbm;
  const int row0 = bm * BM;
  const int col0 = bn * BN;

  const int sr   = tid >> 4;              // 0..15
  const int scol = (tid & 15) << 2;       // 0..60 step 4
  const int swzc = scol ^ ((sr & 7) << 3);

  const float* Abase = A + (size_t)(row0 + sr) * K + scol;
  const int*   Qbase = Q + (size_t)(col0 + sr) * K + scol;

  f32x4 acc[2][4];
#pragma unroll
  for (int i = 0; i < 2; ++i)
#pragma unroll
    for (int j = 0; j < 4; ++j) acc[i][j] = (f32x4)0.0f;

  // named prefetch register sets (rule #20: no pointer-indexed aggregates)
  float4 a0_0, a0_1, a0_2, a0_3;
  float4 a1_0, a1_1, a1_2, a1_3;
  int4 q0_0, q0_1, q0_2, q0_3, q0_4, q0_5, q0_6, q0_7;
  int4 q1_0, q1_1, q1_2, q1_3, q1_4, q1_5, q1_6, q1_7;

  const int NT = K / BK;                  // 64 (even)

  LOADS(0, 0);
  LOADS(1, BK);
  __builtin_amdgcn_sched_barrier(0);
  STORES(0, 0);
  BAR();

  for (int t = 0; t < NT; t += 2) {
    // ---- tile t from buf0 ----
    if (t + 2 < NT) LOADS(0, (t + 2) * BK);
    __builtin_amdgcn_sched_barrier(0);   // loads may not sink below
    COMPUTE(0);
    STORES(1, 1);                        // waits only set1's (old) loads
    BAR();

    // ---- tile t+1 from buf1 ----
    if (t + 3 < NT) LOADS(1, (t + 3) * BK);
    __builtin_amdgcn_sched_barrier(0);
    COMPUTE(1);
    if (t + 2 < NT) STORES(0, 0);
    BAR();
  }

  // epilogue: D col = lane&15 (n), row = (lane>>4)*4 + reg (m)  [m89/m91]
  const int cl = lane & 15;
  const int rb = row0 + wr * 32 + ((lane >> 4) << 2);
  float rs128[2][4];
#pragma unroll
  for (int mi = 0; mi < 2; ++mi)
#pragma unroll
    for (int r = 0; r < 4; ++r)
      rs128[mi][r] = 128.0f * rowsum[rb + mi * 16 + r];

#pragma unroll
  for (int ni = 0; ni < 4; ++ni) {
    const int n = col0 + wc * 64 + ni * 16 + cl;
    const float s = scale[n];
    const float b = bias[n];
#pragma unroll
    for (int mi = 0; mi < 2; ++mi) {
#pragma unroll
      for (int r = 0; r < 4; ++r) {
        C[(size_t)(rb + mi * 16 + r) * N + n] = (acc[mi][ni][r] - rs128[mi][r]) * s + b;
      }
    }
  }
}

extern "C" void kernel_launch(void* const* d_in, const int* in_sizes, int n_in,
                              void* d_out, int out_size, void* d_ws, size_t ws_size,
                              hipStream_t stream) {
  const float* inp   = (const float*)d_in[0];
  const int*   qw    = (const int*)d_in[1];
  const float* scale = (const float*)d_in[2];
  const float* bias  = (const float*)d_in[3];
  float*       out   = (float*)d_out;
  float*       rs    = (float*)d_ws;

  const int OUT = in_sizes[3];            // 11008
  const int IN  = in_sizes[1] / OUT;      // 4096
  const int M   = in_sizes[0] / IN;       // 512

  rowsum_kernel<<<M, 256, 0, stream>>>(inp, rs, IN);

  const int grid = (M / BM) * (OUT / BN); // 688
  qlinear_kernel<<<grid, 256, 0, stream>>>(inp, qw, scale, bias, rs, out, M, OUT, IN);
}

// Round 5
// 351.296 us; speedup vs baseline: 1.7938x; 1.0197x over previous
//
#include <hip/hip_runtime.h>
#include <hip/hip_bf16.h>

// QuantLinear: out[m][n] = (sum_k in[m][k]*(q[n][k]-128)) * scale[n] + bias[n]
// M=512, K=4096, N=11008. A fp32, Q int32 (0..255), out fp32.
// R5: STRAIGHT-LINE main loop. R3/R4's if-guarded prefetch loads lived in
// their own basic blocks -> MachineSink moved them next to their stores
// (sched_barrier only fences within a scheduling region); VGPR=120 both
// rounds proved only one prefetch set was ever live. Now: no branches in the
// loop body, clamped prefetch offsets, so loads stay pinned at the top and
// STORES of the *other* set get counted vmcnt (T4), not a drain.

#define BM 64
#define BN 128
#define BK 64

typedef __attribute__((ext_vector_type(8))) short bf16x8;
typedef __attribute__((ext_vector_type(4))) float f32x4;
typedef __attribute__((ext_vector_type(4))) int   i32x4;

__device__ __forceinline__ unsigned short f2bf(float x) {
  __hip_bfloat16 h = __float2bfloat16(x);
  return *reinterpret_cast<unsigned short*>(&h);
}

__global__ __launch_bounds__(256)
void rowsum_kernel(const float* __restrict__ A, float* __restrict__ rs, int K) {
  const int row = blockIdx.x;
  const int tid = threadIdx.x;
  const float4* Ar = reinterpret_cast<const float4*>(A + (size_t)row * K);
  const int nv4 = K >> 2;
  float s = 0.f;
  for (int i = tid; i < nv4; i += 256) {
    float4 v = Ar[i];
    s += (v.x + v.y) + (v.z + v.w);
  }
#pragma unroll
  for (int off = 32; off > 0; off >>= 1) s += __shfl_down(s, off, 64);
  __shared__ float ws[4];
  if ((tid & 63) == 0) ws[tid >> 6] = s;
  __syncthreads();
  if (tid == 0) rs[row] = (ws[0] + ws[1]) + (ws[2] + ws[3]);
}

// ---- macros over NAMED registers; all offsets compile-time or SALU ----
#define LOADS(s, ke) do {                                                   \
  a##s##_0 = *(const f32x4*)(Abase + (size_t)( 0) * K + (ke));              \
  a##s##_1 = *(const f32x4*)(Abase + (size_t)(16) * K + (ke));              \
  a##s##_2 = *(const f32x4*)(Abase + (size_t)(32) * K + (ke));              \
  a##s##_3 = *(const f32x4*)(Abase + (size_t)(48) * K + (ke));              \
  q##s##_0 = *(const i32x4*)(Qbase + (size_t)(  0) * K + (ke));             \
  q##s##_1 = *(const i32x4*)(Qbase + (size_t)( 16) * K + (ke));             \
  q##s##_2 = *(const i32x4*)(Qbase + (size_t)( 32) * K + (ke));             \
  q##s##_3 = *(const i32x4*)(Qbase + (size_t)( 48) * K + (ke));             \
  q##s##_4 = *(const i32x4*)(Qbase + (size_t)( 64) * K + (ke));             \
  q##s##_5 = *(const i32x4*)(Qbase + (size_t)( 80) * K + (ke));             \
  q##s##_6 = *(const i32x4*)(Qbase + (size_t)( 96) * K + (ke));             \
  q##s##_7 = *(const i32x4*)(Qbase + (size_t)(112) * K + (ke));             \
} while (0)

#define ST_A(b, it, reg) do {                                               \
  ushort4 h;                                                                \
  h.x = f2bf(reg.x); h.y = f2bf(reg.y); h.z = f2bf(reg.z); h.w = f2bf(reg.w); \
  *(ushort4*)&sA[b][(it)*16 + sr][swzc] = h;                                \
} while (0)

#define ST_Q(b, it, reg) do {                                               \
  ushort4 h;                                                                \
  h.x = f2bf((float)reg.x); h.y = f2bf((float)reg.y);                       \
  h.z = f2bf((float)reg.z); h.w = f2bf((float)reg.w);                       \
  *(ushort4*)&sB[b][(it)*16 + sr][swzc] = h;                                \
} while (0)

#define STORES(s, b) do {                                                   \
  ST_A(b, 0, a##s##_0); ST_A(b, 1, a##s##_1);                               \
  ST_A(b, 2, a##s##_2); ST_A(b, 3, a##s##_3);                               \
  ST_Q(b, 0, q##s##_0); ST_Q(b, 1, q##s##_1);                               \
  ST_Q(b, 2, q##s##_2); ST_Q(b, 3, q##s##_3);                               \
  ST_Q(b, 4, q##s##_4); ST_Q(b, 5, q##s##_5);                               \
  ST_Q(b, 6, q##s##_6); ST_Q(b, 7, q##s##_7);                               \
} while (0)

#define COMPUTE(b) do {                                                     \
  _Pragma("unroll")                                                         \
  for (int kk = 0; kk < BK; kk += 32) {                                     \
    const int kb  = (kk + ((lane >> 4) << 3)) ^ ((lane & 7) << 3);          \
    bf16x8 af0 = *(const bf16x8*)&sA[b][wr*32 +  0 + (lane & 15)][kb];      \
    bf16x8 af1 = *(const bf16x8*)&sA[b][wr*32 + 16 + (lane & 15)][kb];      \
    bf16x8 bv0 = *(const bf16x8*)&sB[b][wc*64 +  0 + (lane & 15)][kb];      \
    bf16x8 bv1 = *(const bf16x8*)&sB[b][wc*64 + 16 + (lane & 15)][kb];      \
    bf16x8 bv2 = *(const bf16x8*)&sB[b][wc*64 + 32 + (lane & 15)][kb];      \
    bf16x8 bv3 = *(const bf16x8*)&sB[b][wc*64 + 48 + (lane & 15)][kb];      \
    acc[0][0] = __builtin_amdgcn_mfma_f32_16x16x32_bf16(af0, bv0, acc[0][0], 0,0,0); \
    acc[0][1] = __builtin_amdgcn_mfma_f32_16x16x32_bf16(af0, bv1, acc[0][1], 0,0,0); \
    acc[0][2] = __builtin_amdgcn_mfma_f32_16x16x32_bf16(af0, bv2, acc[0][2], 0,0,0); \
    acc[0][3] = __builtin_amdgcn_mfma_f32_16x16x32_bf16(af0, bv3, acc[0][3], 0,0,0); \
    acc[1][0] = __builtin_amdgcn_mfma_f32_16x16x32_bf16(af1, bv0, acc[1][0], 0,0,0); \
    acc[1][1] = __builtin_amdgcn_mfma_f32_16x16x32_bf16(af1, bv1, acc[1][1], 0,0,0); \
    acc[1][2] = __builtin_amdgcn_mfma_f32_16x16x32_bf16(af1, bv2, acc[1][2], 0,0,0); \
    acc[1][3] = __builtin_amdgcn_mfma_f32_16x16x32_bf16(af1, bv3, acc[1][3], 0,0,0); \
  }                                                                         \
} while (0)

#define BAR() do {                                                          \
  asm volatile("s_waitcnt lgkmcnt(0)" ::: "memory");                        \
  __builtin_amdgcn_s_barrier();                                             \
} while (0)

__global__ __launch_bounds__(256, 2)
void qlinear_kernel(const float* __restrict__ A,     // [M][K]
                    const int*   __restrict__ Q,     // [N][K]
                    const float* __restrict__ scale, // [N]
                    const float* __restrict__ bias,  // [N]
                    const float* __restrict__ rowsum,// [M]
                    float* __restrict__ C,           // [M][N]
                    int M, int N, int K)
{
  __shared__ unsigned short sA[2][BM][BK];
  __shared__ unsigned short sB[2][BN][BK];

  const int tid  = threadIdx.x;
  const int lane = tid & 63;
  const int wave = tid >> 6;
  const int wr   = wave >> 1;
  const int wc   = wave & 1;

  const int nbm = M / BM;                 // 8
  const int nwg = gridDim.x;              // 688
  int wgid = blockIdx.x;
  if ((nwg & 7) == 0) wgid = (wgid & 7) * (nwg >> 3) + (wgid >> 3);
  const int bm   = wgid % nbm;
  const int bn   = wgid / nbm;
  const int row0 = bm * BM;
  const int col0 = bn * BN;

  const int sr   = tid >> 4;              // 0..15
  const int scol = (tid & 15) << 2;       // 0..60 step 4
  const int swzc = scol ^ ((sr & 7) << 3);

  const float* Abase = A + (size_t)(row0 + sr) * K + scol;
  const int*   Qbase = Q + (size_t)(col0 + sr) * K + scol;

  f32x4 acc[2][4];
#pragma unroll
  for (int i = 0; i < 2; ++i)
#pragma unroll
    for (int j = 0; j < 4; ++j) acc[i][j] = (f32x4)0.0f;

  // named prefetch register sets
  f32x4 a0_0, a0_1, a0_2, a0_3;
  f32x4 a1_0, a1_1, a1_2, a1_3;
  i32x4 q0_0, q0_1, q0_2, q0_3, q0_4, q0_5, q0_6, q0_7;
  i32x4 q1_0, q1_1, q1_2, q1_3, q1_4, q1_5, q1_6, q1_7;

  const int NT = K / BK;                  // 64 (even)

  LOADS(0, 0);
  LOADS(1, BK);
  __builtin_amdgcn_sched_barrier(0);
  STORES(0, 0);
  BAR();

#pragma unroll 1
  for (int t = 0; t < NT; t += 2) {
    // clamped prefetch offsets: final iterations redundantly reload tile
    // NT-1 and store it into the buffer that was just consumed — harmless,
    // and it keeps this whole loop body a single branch-free basic block.
    const int ke0 = (t + 2 < NT ? t + 2 : NT - 1) * BK;
    const int ke1 = (t + 3 < NT ? t + 3 : NT - 1) * BK;

    // ---- tile t from buf0 ----
    LOADS(0, ke0);
    __builtin_amdgcn_sched_barrier(0);   // fence: loads stay issued here
    COMPUTE(0);
    STORES(1, 1);                        // counted vmcnt: waits set1 only
    BAR();

    // ---- tile t+1 from buf1 ----
    LOADS(1, ke1);
    __builtin_amdgcn_sched_barrier(0);
    COMPUTE(1);
    STORES(0, 0);
    BAR();
  }

  // epilogue: D col = lane&15 (n), row = (lane>>4)*4 + reg (m)  [m89/m91]
  const int cl = lane & 15;
  const int rb = row0 + wr * 32 + ((lane >> 4) << 2);
  float rs128[2][4];
#pragma unroll
  for (int mi = 0; mi < 2; ++mi)
#pragma unroll
    for (int r = 0; r < 4; ++r)
      rs128[mi][r] = 128.0f * rowsum[rb + mi * 16 + r];

#pragma unroll
  for (int ni = 0; ni < 4; ++ni) {
    const int n = col0 + wc * 64 + ni * 16 + cl;
    const float s = scale[n];
    const float b = bias[n];
#pragma unroll
    for (int mi = 0; mi < 2; ++mi) {
#pragma unroll
      for (int r = 0; r < 4; ++r) {
        C[(size_t)(rb + mi * 16 + r) * N + n] = (acc[mi][ni][r] - rs128[mi][r]) * s + b;
      }
    }
  }
}

extern "C" void kernel_launch(void* const* d_in, const int* in_sizes, int n_in,
                              void* d_out, int out_size, void* d_ws, size_t ws_size,
                              hipStream_t stream) {
  const float* inp   = (const float*)d_in[0];
  const int*   qw    = (const int*)d_in[1];
  const float* scale = (const float*)d_in[2];
  const float* bias  = (const float*)d_in[3];
  float*       out   = (float*)d_out;
  float*       rs    = (float*)d_ws;

  const int OUT = in_sizes[3];            // 11008
  const int IN  = in_sizes[1] / OUT;      // 4096
  const int M   = in_sizes[0] / IN;       // 512

  rowsum_kernel<<<M, 256, 0, stream>>>(inp, rs, IN);

  const int grid = (M / BM) * (OUT / BN); // 688
  qlinear_kernel<<<grid, 256, 0, stream>>>(inp, qw, scale, bias, rs, out, M, OUT, IN);
}